// Round 5
// baseline (39619.968 us; speedup 1.0000x reference)
//
#include <hip/hip_runtime.h>
#include <hip/hip_bf16.h>
#include <hip/hip_cooperative_groups.h>

#define HID   1024
#define BATCH 512
#define SEQ   256
#define OUTD  64
#define NGATE 4096
#define NBLK  256
#define NTHR  1024

typedef __attribute__((ext_vector_type(8))) short bf16x8;
typedef __attribute__((ext_vector_type(4))) float f32x4;
typedef unsigned short u16;

// dynamic LDS: [0,64K) W0 frags, [64K,128K) W1 frags, [128K,+20K) gate slabs (16 waves)
#define LDS_BYTES (131072 + 16 * 1280)

__device__ __forceinline__ u16 f2bf(float v) {
  union { float f; unsigned u; } u; u.f = v;
  unsigned r = u.u + 0x7fffu + ((u.u >> 16) & 1u);
  return (u16)(r >> 16);
}
__device__ __forceinline__ float bf2f(u16 b) {
  union { unsigned u; float f; } u; u.u = ((unsigned)b) << 16;
  return u.f;
}
__device__ __forceinline__ float sigf(float x) { return 1.0f / (1.0f + __expf(-x)); }
__device__ __forceinline__ float tanh_fast(float x) {
  float ax = fabsf(x);
  float e = __expf(-2.0f * ax);
  return copysignf((1.0f - e) / (1.0f + e), x);
}

// fragment-order index for W slabs: block b=np>>4 owns gate rows [16b,16b+16).
// frag f=k>>5 (512 elems, 1KB): elem[(q*16+nl)*8+e] = W[n'=16b+nl][k=f*32+q*8+e]
__device__ __forceinline__ size_t fragidx(int np, int k) {
  int b = np >> 4, nl = np & 15;
  int f = k >> 5, q = (k >> 3) & 3, e = k & 7;
  return ((size_t)b * 64 + f) * 512 + (q * 16 + nl) * 8 + e;
}

// ---------------- prepass kernels ----------------

// W0cat rows (gate-interleaved n'=4j+g): k<1024 -> W_hh0 ; k>=1024 -> Weff = W_ih0 @ fc_out_w
__global__ void k_build_w0f(const float* __restrict__ Whh0, const float* __restrict__ Wih0,
                            const float* __restrict__ fcw, u16* __restrict__ w0f) {
  int np = blockIdx.x;
  int j = np >> 2, g = np & 3;
  int orig = g * 1024 + j;
  int tid = threadIdx.x;
  __shared__ float wrow[64];
  if (tid < 64) wrow[tid] = Wih0[orig * 64 + tid];
  __syncthreads();
  for (int k = tid; k < 1024; k += 256) {
    w0f[fragidx(np, k)] = f2bf(Whh0[(size_t)orig * 1024 + k]);
    float acc = 0.f;
#pragma unroll
    for (int o = 0; o < 64; ++o) acc += wrow[o] * fcw[o * 1024 + k];
    w0f[fragidx(np, 1024 + k)] = f2bf(acc);
  }
}

// W1cat rows: k<1024 -> W_ih1 ; k>=1024 -> W_hh1
__global__ void k_build_w1f(const float* __restrict__ Wih1, const float* __restrict__ Whh1,
                            u16* __restrict__ w1f) {
  int np = blockIdx.x;
  int j = np >> 2, g = np & 3;
  int orig = g * 1024 + j;
  int tid = threadIdx.x;
  for (int k = tid; k < 1024; k += 256) {
    w1f[fragidx(np, k)]        = f2bf(Wih1[(size_t)orig * 1024 + k]);
    w1f[fragidx(np, 1024 + k)] = f2bf(Whh1[(size_t)orig * 1024 + k]);
  }
}

__global__ void k_build_bias(const float* bih0, const float* bhh0,
                             const float* bih1, const float* bhh1,
                             const float* Wih0, const float* fcb,
                             float* bias0b, float* bias0x, float* bias1) {
  int np = blockIdx.x * 256 + threadIdx.x;
  if (np >= NGATE) return;
  int j = np >> 2, g = np & 3;
  int orig = g * 1024 + j;
  bias0b[np] = bih0[orig] + bhh0[orig];
  bias1[np]  = bih1[orig] + bhh1[orig];
  float acc = 0.f;
#pragma unroll
  for (int o = 0; o < 64; ++o) acc += Wih0[orig * 64 + o] * fcb[o];
  bias0x[np] = acc;   // fc_out bias routed through W_ih0 (valid only t>=1; x(0)=0)
}

__global__ void k_fcwb(const float* __restrict__ fcw, u16* __restrict__ fcwb) {
  int idx = blockIdx.x * 256 + threadIdx.x;  // 65536
  fcwb[idx] = f2bf(fcw[idx]);
}

// init_flat = [z|z] @ fc_init_w^T + b, torch-.view scatter into:
// xa0 = [h0_init | 0] (phase-A operand at t=0; upper half 0 => x(0)=0)
// xb0 = [ (written by phase A(0)) | h1_init ] (phase-B operand at t=0)
__global__ void k_init(const float* __restrict__ zs, const float* __restrict__ zk,
                       const float* __restrict__ fiw, const float* __restrict__ fib,
                       u16* __restrict__ xa0, u16* __restrict__ xb0) {
  int r = blockIdx.x;   // 0..511
  int tid = threadIdx.x;
  __shared__ float z[256];
  if (tid < 128) z[tid] = zs[r * 128 + tid];
  else           z[tid] = zk[r * 128 + (tid - 128)];
  __syncthreads();
  for (int h = tid; h < 1024; h += 256)
    xa0[(size_t)r * 2048 + 1024 + h] = 0;    // x-source at t=0 is zero
  for (int c = tid; c < 2048; c += 256) {
    float acc = fib[c];
    const float* w = fiw + (size_t)c * 256;
#pragma unroll 8
    for (int k = 0; k < 256; ++k) acc += z[k] * w[k];
    int l = (r >= 256) ? 1 : 0;
    int b = 2 * (r - l * 256) + (c >> 10);
    int h = c & 1023;
    u16 v = f2bf(acc);
    if (l == 0) xa0[(size_t)b * 2048 + h] = v;
    else        xb0[(size_t)b * 2048 + 1024 + h] = v;
  }
}

// ---------------- main cooperative kernel ----------------

struct Params {
  const u16* w0f;
  const u16* w1f;
  const float* bias0b;
  const float* bias0x;
  const float* bias1;
  u16* xa0; u16* xa1;    // phase-A operands [512][2048] = [h0_prev | h1_prev]
  u16* xb0; u16* xb1;    // phase-B operands [512][2048] = [h0_new  | h1_prev]
  const u16* fcwb;       // [64][1024] bf16
  const float* fcb;
  float* out;            // [512][256][64]
  unsigned* flags;       // [512 intervals][256 blocks]
};

// lightweight grid barrier: per-interval flag array, wave-0 polls with agent loads
__device__ __forceinline__ void gbar(unsigned* flags, int i, int blk, int tid) {
  __syncthreads();
  if (tid < 64) {
    unsigned* f = flags + i * NBLK;
    if (tid == 0) {
      __builtin_amdgcn_fence(__ATOMIC_RELEASE, "agent");
      __hip_atomic_store(&f[blk], 1u, __ATOMIC_RELAXED, __HIP_MEMORY_SCOPE_AGENT);
    }
    while (true) {
      unsigned a = __hip_atomic_load(&f[tid],       __ATOMIC_RELAXED, __HIP_MEMORY_SCOPE_AGENT);
      unsigned b = __hip_atomic_load(&f[tid + 64],  __ATOMIC_RELAXED, __HIP_MEMORY_SCOPE_AGENT);
      unsigned c = __hip_atomic_load(&f[tid + 128], __ATOMIC_RELAXED, __HIP_MEMORY_SCOPE_AGENT);
      unsigned d = __hip_atomic_load(&f[tid + 192], __ATOMIC_RELAXED, __HIP_MEMORY_SCOPE_AGENT);
      if (__ballot((a & b & c & d) == 1u) == ~0ull) break;
      __builtin_amdgcn_s_sleep(1);
    }
    if (tid == 0) __builtin_amdgcn_fence(__ATOMIC_ACQUIRE, "agent");
  }
  __syncthreads();
}

// gates tile [512 m x 16 n] = X @ Wslice^T (X = [h|h] contiguous 2048-k stream),
// LDS-persistent W, depth-4 named-register prefetch, fused cell, dual-dest h write.
// Wave covers m rows [32*wave, 32*wave+32) as 2 m-frags.
__device__ __forceinline__ void gemm_cell(
    const u16* __restrict__ X, const u16* __restrict__ lw, float* cr,
    u16* __restrict__ d1, u16* __restrict__ d2,
    const float* bg, const float* bx, bool ubx,
    int blk, int lane, int wave, float* slab)
{
  const int lr = lane & 15, lq = lane >> 4;
  const u16* A0 = X + (size_t)(wave * 32 + lr) * 2048 + lq * 8;
  const u16* A1 = A0 + 16 * 2048;
  const u16* Wb = lw + lane * 8;

  f32x4 acc0 = {0, 0, 0, 0}, acc1 = {0, 0, 0, 0};
  // depth-4 software pipeline, named scalars only (spill-proof)
  bf16x8 s0a = *(const bf16x8*)(A0 +  0), s0b = *(const bf16x8*)(A1 +  0);
  bf16x8 s1a = *(const bf16x8*)(A0 + 32), s1b = *(const bf16x8*)(A1 + 32);
  bf16x8 s2a = *(const bf16x8*)(A0 + 64), s2b = *(const bf16x8*)(A1 + 64);
  bf16x8 s3a = *(const bf16x8*)(A0 + 96), s3b = *(const bf16x8*)(A1 + 96);

#pragma unroll
  for (int g = 0; g < 16; ++g) {
    {
      bf16x8 wf = *(const bf16x8*)(Wb + (4 * g + 0) * 512);
      acc0 = __builtin_amdgcn_mfma_f32_16x16x32_bf16(s0a, wf, acc0, 0, 0, 0);
      acc1 = __builtin_amdgcn_mfma_f32_16x16x32_bf16(s0b, wf, acc1, 0, 0, 0);
      if (g < 15) { s0a = *(const bf16x8*)(A0 + (4 * g + 4) * 32);
                    s0b = *(const bf16x8*)(A1 + (4 * g + 4) * 32); }
    }
    {
      bf16x8 wf = *(const bf16x8*)(Wb + (4 * g + 1) * 512);
      acc0 = __builtin_amdgcn_mfma_f32_16x16x32_bf16(s1a, wf, acc0, 0, 0, 0);
      acc1 = __builtin_amdgcn_mfma_f32_16x16x32_bf16(s1b, wf, acc1, 0, 0, 0);
      if (g < 15) { s1a = *(const bf16x8*)(A0 + (4 * g + 5) * 32);
                    s1b = *(const bf16x8*)(A1 + (4 * g + 5) * 32); }
    }
    {
      bf16x8 wf = *(const bf16x8*)(Wb + (4 * g + 2) * 512);
      acc0 = __builtin_amdgcn_mfma_f32_16x16x32_bf16(s2a, wf, acc0, 0, 0, 0);
      acc1 = __builtin_amdgcn_mfma_f32_16x16x32_bf16(s2b, wf, acc1, 0, 0, 0);
      if (g < 15) { s2a = *(const bf16x8*)(A0 + (4 * g + 6) * 32);
                    s2b = *(const bf16x8*)(A1 + (4 * g + 6) * 32); }
    }
    {
      bf16x8 wf = *(const bf16x8*)(Wb + (4 * g + 3) * 512);
      acc0 = __builtin_amdgcn_mfma_f32_16x16x32_bf16(s3a, wf, acc0, 0, 0, 0);
      acc1 = __builtin_amdgcn_mfma_f32_16x16x32_bf16(s3b, wf, acc1, 0, 0, 0);
      if (g < 15) { s3a = *(const bf16x8*)(A0 + (4 * g + 7) * 32);
                    s3b = *(const bf16x8*)(A1 + (4 * g + 7) * 32); }
    }
  }

  // per-wave slab round-trip (wave-synchronous): C layout (row=quad*4+reg, col=lane&15)
  const int rr = lane & 3, jl = (lane >> 2) & 3;
#pragma unroll
  for (int mf = 0; mf < 2; ++mf) {
    f32x4 av = (mf == 0) ? acc0 : acc1;
#pragma unroll
    for (int r2 = 0; r2 < 4; ++r2)
      slab[(lq * 4 + r2) * 20 + lr] = av[r2];
    f32x4 g4 = *(f32x4*)&slab[(lq * 4 + rr) * 20 + 4 * jl];
    float gi = g4[0] + bg[0] + (ubx ? bx[0] : 0.f);
    float gf = g4[1] + bg[1] + (ubx ? bx[1] : 0.f);
    float gg = g4[2] + bg[2] + (ubx ? bx[2] : 0.f);
    float go = g4[3] + bg[3] + (ubx ? bx[3] : 0.f);
    float iv = sigf(gi), fv = sigf(gf), gv = tanh_fast(gg), ov = sigf(go);
    float cnew = fv * cr[mf] + iv * gv;
    float hnew = ov * tanh_fast(cnew);
    cr[mf] = cnew;
    int m = wave * 32 + mf * 16 + lq * 4 + rr;
    u16 hv = f2bf(hnew);
    d1[(size_t)m * 2048 + blk * 4 + jl] = hv;   // next phase-B operand
    d2[(size_t)m * 2048 + blk * 4 + jl] = hv;   // next phase-A operand
  }
}

// out(tq) for this block's 2 batch rows over 16 waves: 8 dots/wave, 8-way k-split.
__device__ __forceinline__ void out_proj(const u16* __restrict__ Xsrc, const Params& p,
                                         int blk, int lane, int wave, int tq) {
  int dl = lane >> 3, ks = lane & 7;
  int dg = wave * 8 + dl;             // 0..127
  int row = dg >> 6, o = dg & 63;
  int b = 2 * blk + row;
  const u16* h = Xsrc + (size_t)b * 2048 + 1024 + ks * 128;
  const u16* w = p.fcwb + (size_t)o * 1024 + ks * 128;
  float acc = 0.f;
#pragma unroll
  for (int kk = 0; kk < 128; kk += 8) {
    bf16x8 hv = *(const bf16x8*)(h + kk);
    bf16x8 wv = *(const bf16x8*)(w + kk);
#pragma unroll
    for (int j = 0; j < 8; ++j)
      acc += bf2f(((u16*)&hv)[j]) * bf2f(((u16*)&wv)[j]);
  }
  acc += __shfl_xor(acc, 1);
  acc += __shfl_xor(acc, 2);
  acc += __shfl_xor(acc, 4);
  if (ks == 0) p.out[((size_t)b * SEQ + tq) * OUTD + o] = acc + p.fcb[o];
}

__global__ __launch_bounds__(NTHR, 4)
void k_lstm(Params p) {
  extern __shared__ char smem[];
  const int blk = blockIdx.x, tid = threadIdx.x;
  const int lane = tid & 63, wave = tid >> 6;

  u16* lw0 = (u16*)smem;
  u16* lw1 = (u16*)(smem + 65536);
  float* slab = (float*)(smem + 131072) + wave * 320;

  // one-time: block's W slices -> LDS (linear, frag-ordered)
  {
    const u16* g0 = p.w0f + (size_t)blk * 32768;
    const u16* g1 = p.w1f + (size_t)blk * 32768;
    for (int i = tid * 8; i < 32768; i += NTHR * 8) {
      *(bf16x8*)(lw0 + i) = *(const bf16x8*)(g0 + i);
      *(bf16x8*)(lw1 + i) = *(const bf16x8*)(g1 + i);
    }
  }
  const int jg = blk * 4 + ((lane >> 2) & 3);
  float b0r[4], bxr[4], b1r[4];
  float c0r[2] = {0, 0}, c1r[2] = {0, 0};
#pragma unroll
  for (int g = 0; g < 4; ++g) {
    b0r[g] = p.bias0b[4 * jg + g];
    bxr[g] = p.bias0x[4 * jg + g];
    b1r[g] = p.bias1[4 * jg + g];
  }
  __syncthreads();

  int bar = 0;
  for (int t = 0; t < SEQ; ++t) {
    const int pr = t & 1;
    u16* xap = pr ? p.xa1 : p.xa0;   // phase-A operand (t parity)
    u16* xan = pr ? p.xa0 : p.xa1;   // next phase-A operand
    u16* xbp = pr ? p.xb1 : p.xb0;   // phase-B operand
    u16* xbn = pr ? p.xb0 : p.xb1;   // next phase-B operand
    // ---- phase A: gates0 = xap @ W0^T ; h0(t) -> xbp.h0half + xan.h0half ----
    if (t > 0) out_proj(xap, p, blk, lane, wave, t - 1);   // out(t-1) from xap.h1half
    gemm_cell(xap, lw0, c0r, xbp, xan, b0r, bxr, t > 0, blk, lane, wave, slab);
    gbar(p.flags, bar++, blk, tid);
    // ---- phase B: gates1 = xbp @ W1^T ; h1(t) -> xan.h1half + xbn.h1half ----
    gemm_cell(xbp, lw1, c1r, xan + 1024, xbn + 1024, b1r, nullptr, false, blk, lane, wave, slab);
    gbar(p.flags, bar++, blk, tid);
  }
  out_proj(p.xa0, p, blk, lane, wave, SEQ - 1);   // h1(255) in xa0.h1half
}

// ---------------- launch ----------------

extern "C" void kernel_launch(void* const* d_in, const int* in_sizes, int n_in,
                              void* d_out, int out_size, void* d_ws, size_t ws_size,
                              hipStream_t stream) {
  const float* zs   = (const float*)d_in[0];
  const float* zk   = (const float*)d_in[1];
  const float* fiw  = (const float*)d_in[2];
  const float* fib  = (const float*)d_in[3];
  const float* Wih0 = (const float*)d_in[4];
  const float* Whh0 = (const float*)d_in[5];
  const float* bih0 = (const float*)d_in[6];
  const float* bhh0 = (const float*)d_in[7];
  const float* Wih1 = (const float*)d_in[8];
  const float* Whh1 = (const float*)d_in[9];
  const float* bih1 = (const float*)d_in[10];
  const float* bhh1 = (const float*)d_in[11];
  const float* fcw  = (const float*)d_in[12];
  const float* fcb  = (const float*)d_in[13];
  float* out = (float*)d_out;

  char* ws = (char*)d_ws;
  size_t off = 0;
  auto alloc = [&](size_t bytes) -> char* {
    char* pp = ws + off;
    off += (bytes + 255) & ~(size_t)255;
    return pp;
  };
  u16* w0f  = (u16*)alloc((size_t)NGATE * 2048 * 2);
  u16* w1f  = (u16*)alloc((size_t)NGATE * 2048 * 2);
  u16* xa0  = (u16*)alloc((size_t)BATCH * 2048 * 2);
  u16* xa1  = (u16*)alloc((size_t)BATCH * 2048 * 2);
  u16* xb0  = (u16*)alloc((size_t)BATCH * 2048 * 2);
  u16* xb1  = (u16*)alloc((size_t)BATCH * 2048 * 2);
  u16* fcwb = (u16*)alloc((size_t)OUTD * HID * 2);
  float* bias0b = (float*)alloc(NGATE * 4);
  float* bias0x = (float*)alloc(NGATE * 4);
  float* bias1  = (float*)alloc(NGATE * 4);
  unsigned* flags = (unsigned*)alloc((size_t)2 * SEQ * NBLK * 4);

  hipMemsetAsync(flags, 0, (size_t)2 * SEQ * NBLK * 4, stream);

  hipLaunchKernelGGL(k_build_w0f, dim3(NGATE), dim3(256), 0, stream, Whh0, Wih0, fcw, w0f);
  hipLaunchKernelGGL(k_build_w1f, dim3(NGATE), dim3(256), 0, stream, Wih1, Whh1, w1f);
  hipLaunchKernelGGL(k_build_bias, dim3(16), dim3(256), 0, stream,
                     bih0, bhh0, bih1, bhh1, Wih0, fcb, bias0b, bias0x, bias1);
  hipLaunchKernelGGL(k_fcwb, dim3(256), dim3(256), 0, stream, fcw, fcwb);
  hipLaunchKernelGGL(k_init, dim3(BATCH), dim3(256), 0, stream, zs, zk, fiw, fib, xa0, xb0);

  Params prm;
  prm.w0f = w0f; prm.w1f = w1f;
  prm.bias0b = bias0b; prm.bias0x = bias0x; prm.bias1 = bias1;
  prm.xa0 = xa0; prm.xa1 = xa1; prm.xb0 = xb0; prm.xb1 = xb1;
  prm.fcwb = fcwb; prm.fcb = fcb; prm.out = out;
  prm.flags = flags;

  hipFuncSetAttribute((const void*)k_lstm, hipFuncAttributeMaxDynamicSharedMemorySize, LDS_BYTES);
  void* args[] = { &prm };
  hipLaunchCooperativeKernel((void*)k_lstm, dim3(NBLK), dim3(NTHR), args, LDS_BYTES, stream);
}

// Round 6
// 32517.654 us; speedup vs baseline: 1.2184x; 1.2184x over previous
//
#include <hip/hip_runtime.h>
#include <hip/hip_bf16.h>
#include <hip/hip_cooperative_groups.h>

#define HID   1024
#define BATCH 512
#define SEQ   256
#define OUTD  64
#define NGATE 4096
#define NBLK  256
#define NTHR  512

typedef __attribute__((ext_vector_type(8))) short bf16x8;
typedef __attribute__((ext_vector_type(4))) float f32x4;
typedef unsigned short u16;

// dynamic LDS: xs0 [64][520] bf16 (66560 B), xs1 (66560 B), slabs 8 x 1280 B
#define XS_STRIDE 520
#define XS_BYTES  (64 * XS_STRIDE * 2)
#define LDS_BYTES (2 * XS_BYTES + 8 * 1280)

__device__ __forceinline__ u16 f2bf(float v) {
  union { float f; unsigned u; } u; u.f = v;
  unsigned r = u.u + 0x7fffu + ((u.u >> 16) & 1u);
  return (u16)(r >> 16);
}
__device__ __forceinline__ float bf2f(u16 b) {
  union { unsigned u; float f; } u; u.u = ((unsigned)b) << 16;
  return u.f;
}
__device__ __forceinline__ float sigf(float x) { return 1.0f / (1.0f + __expf(-x)); }
__device__ __forceinline__ float tanh_fast(float x) {
  float ax = fabsf(x);
  float e = __expf(-2.0f * ax);
  return copysignf((1.0f - e) / (1.0f + e), x);
}

// fragment-order index for W slabs: slab s=np>>4 owns gate rows [16s,16s+16).
// frag f=k>>5 (512 elems, 1KB): elem[(q*16+nl)*8+e] = W[n'=16s+nl][k=f*32+q*8+e]
__device__ __forceinline__ size_t fragidx(int np, int k) {
  int b = np >> 4, nl = np & 15;
  int f = k >> 5, q = (k >> 3) & 3, e = k & 7;
  return ((size_t)b * 64 + f) * 512 + (q * 16 + nl) * 8 + e;
}

// ---------------- prepass kernels (unchanged, verified) ----------------

__global__ void k_build_w0f(const float* __restrict__ Whh0, const float* __restrict__ Wih0,
                            const float* __restrict__ fcw, u16* __restrict__ w0f) {
  int np = blockIdx.x;
  int j = np >> 2, g = np & 3;
  int orig = g * 1024 + j;
  int tid = threadIdx.x;
  __shared__ float wrow[64];
  if (tid < 64) wrow[tid] = Wih0[orig * 64 + tid];
  __syncthreads();
  for (int k = tid; k < 1024; k += 256) {
    w0f[fragidx(np, k)] = f2bf(Whh0[(size_t)orig * 1024 + k]);
    float acc = 0.f;
#pragma unroll
    for (int o = 0; o < 64; ++o) acc += wrow[o] * fcw[o * 1024 + k];
    w0f[fragidx(np, 1024 + k)] = f2bf(acc);
  }
}

__global__ void k_build_w1f(const float* __restrict__ Wih1, const float* __restrict__ Whh1,
                            u16* __restrict__ w1f) {
  int np = blockIdx.x;
  int j = np >> 2, g = np & 3;
  int orig = g * 1024 + j;
  int tid = threadIdx.x;
  for (int k = tid; k < 1024; k += 256) {
    w1f[fragidx(np, k)]        = f2bf(Wih1[(size_t)orig * 1024 + k]);
    w1f[fragidx(np, 1024 + k)] = f2bf(Whh1[(size_t)orig * 1024 + k]);
  }
}

__global__ void k_build_bias(const float* bih0, const float* bhh0,
                             const float* bih1, const float* bhh1,
                             const float* Wih0, const float* fcb,
                             float* bias0b, float* bias0x, float* bias1) {
  int np = blockIdx.x * 256 + threadIdx.x;
  if (np >= NGATE) return;
  int j = np >> 2, g = np & 3;
  int orig = g * 1024 + j;
  bias0b[np] = bih0[orig] + bhh0[orig];
  bias1[np]  = bih1[orig] + bhh1[orig];
  float acc = 0.f;
#pragma unroll
  for (int o = 0; o < 64; ++o) acc += Wih0[orig * 64 + o] * fcb[o];
  bias0x[np] = acc;   // fc_out bias routed through W_ih0 (valid only t>=1; x(0)=0)
}

__global__ void k_fcwb(const float* __restrict__ fcw, u16* __restrict__ fcwb) {
  int idx = blockIdx.x * 256 + threadIdx.x;  // 65536
  fcwb[idx] = f2bf(fcw[idx]);
}

__global__ void k_init(const float* __restrict__ zs, const float* __restrict__ zk,
                       const float* __restrict__ fiw, const float* __restrict__ fib,
                       u16* __restrict__ xa0, u16* __restrict__ xb0) {
  int r = blockIdx.x;
  int tid = threadIdx.x;
  __shared__ float z[256];
  if (tid < 128) z[tid] = zs[r * 128 + tid];
  else           z[tid] = zk[r * 128 + (tid - 128)];
  __syncthreads();
  for (int h = tid; h < 1024; h += 256)
    xa0[(size_t)r * 2048 + 1024 + h] = 0;    // x-source at t=0 is zero
  for (int c = tid; c < 2048; c += 256) {
    float acc = fib[c];
    const float* w = fiw + (size_t)c * 256;
#pragma unroll 8
    for (int k = 0; k < 256; ++k) acc += z[k] * w[k];
    int l = (r >= 256) ? 1 : 0;
    int b = 2 * (r - l * 256) + (c >> 10);
    int h = c & 1023;
    u16 v = f2bf(acc);
    if (l == 0) xa0[(size_t)b * 2048 + h] = v;
    else        xb0[(size_t)b * 2048 + 1024 + h] = v;
  }
}

// ---------------- main cooperative kernel ----------------

struct Params {
  const u16* w0f;        // frag-ordered, 16MB (L3-resident stream)
  const u16* w1f;
  const float* bias0b;
  const float* bias0x;
  const float* bias1;
  u16* xa0; u16* xa1;    // phase-A operands [512][2048] = [h0_prev | h1_prev]
  u16* xb0; u16* xb1;    // phase-B operands [512][2048] = [h0_new  | h1_prev]
  const u16* fcwb;       // [64][1024] bf16
  const float* fcb;
  float* out;            // [512][256][64]
  unsigned* flags;       // [512 bars][8 grp][32 rank]
};

// group barrier: 32 blocks of one batch-group, agent-scope fences for correctness
__device__ __forceinline__ void gbar(unsigned* flags, int bar, int grp, int rank, int tid) {
  __syncthreads();
  if (tid < 64) {
    unsigned* f = flags + (bar * 8 + grp) * 32;
    if (tid == 0)
      __hip_atomic_store(&f[rank], 1u, __ATOMIC_RELEASE, __HIP_MEMORY_SCOPE_AGENT);
    int sl = tid & 31;
    while (true) {
      unsigned v = __hip_atomic_load(&f[sl], __ATOMIC_RELAXED, __HIP_MEMORY_SCOPE_AGENT);
      if (__ballot(v == 1u) == ~0ull) break;
      __builtin_amdgcn_s_sleep(1);
    }
    if (tid == 0) __builtin_amdgcn_fence(__ATOMIC_ACQUIRE, "agent");
  }
  __syncthreads();
}

// gates tile [64 m x 16 n per wave] = Xgroup @ Wslab^T.
// X LDS-staged in 4 k-chunks (double-buffered); W streamed L3->regs depth-8.
__device__ __forceinline__ void gemm_phase(
    const u16* __restrict__ Xg,   // X + grp*64*2048
    const u16* __restrict__ Wp,   // wave's 64KB W slab
    u16* xs0, u16* xs1, int tid, int lane, f32x4 acc[4])
{
  const int lr = lane & 15, lq = lane >> 4;
  const int srow = tid >> 3;             // staging row 0..63
  const int scol = (tid & 7) * 64;       // staging col base (elems)

  bf16x8 w[8];
#pragma unroll
  for (int f = 0; f < 8; ++f)
    w[f] = *(const bf16x8*)(Wp + f * 512 + lane * 8);

  // stage chunk 0
#pragma unroll
  for (int i = 0; i < 8; ++i)
    *(bf16x8*)(xs0 + srow * XS_STRIDE + scol + i * 8) =
        *(const bf16x8*)(Xg + (size_t)srow * 2048 + scol + i * 8);
  __syncthreads();

#pragma unroll
  for (int c = 0; c < 4; ++c) {
    u16* xsc = (c & 1) ? xs1 : xs0;
    u16* xsn = (c & 1) ? xs0 : xs1;
    if (c < 3) {   // stage next chunk concurrently with compute
#pragma unroll
      for (int i = 0; i < 8; ++i)
        *(bf16x8*)(xsn + srow * XS_STRIDE + scol + i * 8) =
            *(const bf16x8*)(Xg + (size_t)srow * 2048 + (c + 1) * 512 + scol + i * 8);
    }
#pragma unroll
    for (int kf = 0; kf < 16; ++kf) {
      const int f = c * 16 + kf;
      bf16x8 wf = w[f & 7];
      if (f < 56) w[f & 7] = *(const bf16x8*)(Wp + (f + 8) * 512 + lane * 8);
      const u16* xb = xsc + lr * XS_STRIDE + kf * 32 + lq * 8;
      acc[0] = __builtin_amdgcn_mfma_f32_16x16x32_bf16(*(const bf16x8*)(xb),                  wf, acc[0], 0, 0, 0);
      acc[1] = __builtin_amdgcn_mfma_f32_16x16x32_bf16(*(const bf16x8*)(xb + 16 * XS_STRIDE), wf, acc[1], 0, 0, 0);
      acc[2] = __builtin_amdgcn_mfma_f32_16x16x32_bf16(*(const bf16x8*)(xb + 32 * XS_STRIDE), wf, acc[2], 0, 0, 0);
      acc[3] = __builtin_amdgcn_mfma_f32_16x16x32_bf16(*(const bf16x8*)(xb + 48 * XS_STRIDE), wf, acc[3], 0, 0, 0);
    }
    __syncthreads();
  }
}

// fused LSTM cell on the wave's [64 m x 16 n] gates; h dual-write (full lines per block)
__device__ __forceinline__ void cell_store(
    f32x4 acc[4], float* cr, u16* __restrict__ d1, u16* __restrict__ d2,
    const float* bg, const float* bx, bool ubx,
    int grp, int jg, int lane, float* slab)
{
  const int lr = lane & 15, lq = lane >> 4;
  const int rr = lane & 3, jl = (lane >> 2) & 3;
  (void)jl;
#pragma unroll
  for (int mf = 0; mf < 4; ++mf) {
#pragma unroll
    for (int r2 = 0; r2 < 4; ++r2)
      slab[(lq * 4 + r2) * 20 + lr] = acc[mf][r2];
    f32x4 g4 = *(f32x4*)&slab[(lq * 4 + rr) * 20 + 4 * ((lane >> 2) & 3)];
    float gi = g4[0] + bg[0] + (ubx ? bx[0] : 0.f);
    float gf = g4[1] + bg[1] + (ubx ? bx[1] : 0.f);
    float gg = g4[2] + bg[2] + (ubx ? bx[2] : 0.f);
    float go = g4[3] + bg[3] + (ubx ? bx[3] : 0.f);
    float iv = sigf(gi), fv = sigf(gf), gv = tanh_fast(gg), ov = sigf(go);
    float cnew = fv * cr[mf] + iv * gv;
    float hnew = ov * tanh_fast(cnew);
    cr[mf] = cnew;
    int m = mf * 16 + lq * 4 + rr;
    size_t row = (size_t)(grp * 64 + m) * 2048;
    u16 hv = f2bf(hnew);
    d1[row + jg] = hv;
    d2[row + jg] = hv;
  }
}

// out(t-1) from the staged h1 chunks (xs0 = h1 cols [0,512), xs1 = [512,1024))
__device__ __forceinline__ void out_proj_lds(const u16* xs0, const u16* xs1,
                                             const Params& p, int grp, int rank,
                                             int tid, int tq) {
  int D = rank * 128 + (tid >> 2);
  int brow = D >> 6, o = D & 63;
  int ks = tid & 3;
  const u16* h = ((ks < 2) ? xs0 : xs1) + brow * XS_STRIDE + (ks & 1) * 256;
  const u16* w = p.fcwb + (size_t)o * 1024 + ks * 256;
  float acc = 0.f;
#pragma unroll 4
  for (int kk = 0; kk < 256; kk += 8) {
    bf16x8 hv = *(const bf16x8*)(h + kk);
    bf16x8 wv = *(const bf16x8*)(w + kk);
#pragma unroll
    for (int j = 0; j < 8; ++j)
      acc += bf2f(((u16*)&hv)[j]) * bf2f(((u16*)&wv)[j]);
  }
  acc += __shfl_xor(acc, 1);
  acc += __shfl_xor(acc, 2);
  if (ks == 0)
    p.out[((size_t)(grp * 64 + brow) * SEQ + tq) * OUTD + o] = acc + p.fcb[o];
}

// final out(SEQ-1): h1 from global buffer
__device__ __forceinline__ void out_proj_g(const u16* __restrict__ Xsrc, const Params& p,
                                           int grp, int rank, int tid, int tq) {
  int D = rank * 128 + (tid >> 2);
  int brow = D >> 6, o = D & 63;
  int ks = tid & 3;
  const u16* h = Xsrc + (size_t)(grp * 64 + brow) * 2048 + 1024 + ks * 256;
  const u16* w = p.fcwb + (size_t)o * 1024 + ks * 256;
  float acc = 0.f;
#pragma unroll 4
  for (int kk = 0; kk < 256; kk += 8) {
    bf16x8 hv = *(const bf16x8*)(h + kk);
    bf16x8 wv = *(const bf16x8*)(w + kk);
#pragma unroll
    for (int j = 0; j < 8; ++j)
      acc += bf2f(((u16*)&hv)[j]) * bf2f(((u16*)&wv)[j]);
  }
  acc += __shfl_xor(acc, 1);
  acc += __shfl_xor(acc, 2);
  if (ks == 0)
    p.out[((size_t)(grp * 64 + brow) * SEQ + tq) * OUTD + o] = acc + p.fcb[o];
}

__global__ __launch_bounds__(NTHR, 2)
void k_lstm(Params p) {
  extern __shared__ char smem[];
  const int blk = blockIdx.x, tid = threadIdx.x;
  const int lane = tid & 63, wave = tid >> 6;
  const int grp = blk & 7;        // batch group (XCD-aligned by %8 heuristic)
  const int rank = blk >> 3;      // rank within group, 0..31

  u16* xs0 = (u16*)smem;
  u16* xs1 = (u16*)(smem + XS_BYTES);
  float* slab = (float*)(smem + 2 * XS_BYTES) + wave * 320;

  const int sid = rank * 8 + wave;     // W slab id 0..255 (16 gate rows each)
  const u16* W0p = p.w0f + (size_t)sid * 32768;
  const u16* W1p = p.w1f + (size_t)sid * 32768;
  const int jg = rank * 32 + wave * 4 + ((lane >> 2) & 3);   // lane's hidden unit

  float b0r[4], bxr[4], b1r[4];
  float c0r[4] = {0, 0, 0, 0}, c1r[4] = {0, 0, 0, 0};
#pragma unroll
  for (int g = 0; g < 4; ++g) {
    b0r[g] = p.bias0b[4 * jg + g];
    bxr[g] = p.bias0x[4 * jg + g];
    b1r[g] = p.bias1[4 * jg + g];
  }

  int bar = 0;
  for (int t = 0; t < SEQ; ++t) {
    const int pr = t & 1;
    u16* xap = pr ? p.xa1 : p.xa0;
    u16* xan = pr ? p.xa0 : p.xa1;
    u16* xbp = pr ? p.xb1 : p.xb0;
    u16* xbn = pr ? p.xb0 : p.xb1;
    // ---- phase A: gates0 = xap @ W0^T ; h0(t) -> xbp.h0 + xan.h0 ----
    {
      f32x4 acc[4] = {{0,0,0,0},{0,0,0,0},{0,0,0,0},{0,0,0,0}};
      gemm_phase(xap + (size_t)grp * 64 * 2048, W0p, xs0, xs1, tid, lane, acc);
      if (t > 0) out_proj_lds(xs0, xs1, p, grp, rank, tid, t - 1); // h1(t-1) staged
      cell_store(acc, c0r, xbp, xan, b0r, bxr, t > 0, grp, jg, lane, slab);
    }
    gbar(p.flags, bar++, grp, rank, tid);
    // ---- phase B: gates1 = xbp @ W1^T ; h1(t) -> xan.h1 + xbn.h1 ----
    {
      f32x4 acc[4] = {{0,0,0,0},{0,0,0,0},{0,0,0,0},{0,0,0,0}};
      gemm_phase(xbp + (size_t)grp * 64 * 2048, W1p, xs0, xs1, tid, lane, acc);
      cell_store(acc, c1r, xan + 1024, xbn + 1024, b1r, nullptr, false, grp, jg, lane, slab);
    }
    gbar(p.flags, bar++, grp, rank, tid);
  }
  out_proj_g(p.xa0, p, grp, rank, tid, SEQ - 1);   // h1(255) in xa0.h1
}

// ---------------- launch ----------------

extern "C" void kernel_launch(void* const* d_in, const int* in_sizes, int n_in,
                              void* d_out, int out_size, void* d_ws, size_t ws_size,
                              hipStream_t stream) {
  const float* zs   = (const float*)d_in[0];
  const float* zk   = (const float*)d_in[1];
  const float* fiw  = (const float*)d_in[2];
  const float* fib  = (const float*)d_in[3];
  const float* Wih0 = (const float*)d_in[4];
  const float* Whh0 = (const float*)d_in[5];
  const float* bih0 = (const float*)d_in[6];
  const float* bhh0 = (const float*)d_in[7];
  const float* Wih1 = (const float*)d_in[8];
  const float* Whh1 = (const float*)d_in[9];
  const float* bih1 = (const float*)d_in[10];
  const float* bhh1 = (const float*)d_in[11];
  const float* fcw  = (const float*)d_in[12];
  const float* fcb  = (const float*)d_in[13];
  float* out = (float*)d_out;

  char* ws = (char*)d_ws;
  size_t off = 0;
  auto alloc = [&](size_t bytes) -> char* {
    char* pp = ws + off;
    off += (bytes + 255) & ~(size_t)255;
    return pp;
  };
  u16* w0f  = (u16*)alloc((size_t)NGATE * 2048 * 2);
  u16* w1f  = (u16*)alloc((size_t)NGATE * 2048 * 2);
  u16* xa0  = (u16*)alloc((size_t)BATCH * 2048 * 2);
  u16* xa1  = (u16*)alloc((size_t)BATCH * 2048 * 2);
  u16* xb0  = (u16*)alloc((size_t)BATCH * 2048 * 2);
  u16* xb1  = (u16*)alloc((size_t)BATCH * 2048 * 2);
  u16* fcwb = (u16*)alloc((size_t)OUTD * HID * 2);
  float* bias0b = (float*)alloc(NGATE * 4);
  float* bias0x = (float*)alloc(NGATE * 4);
  float* bias1  = (float*)alloc(NGATE * 4);
  unsigned* flags = (unsigned*)alloc((size_t)2 * SEQ * 8 * 32 * 4);

  hipMemsetAsync(flags, 0, (size_t)2 * SEQ * 8 * 32 * 4, stream);

  hipLaunchKernelGGL(k_build_w0f, dim3(NGATE), dim3(256), 0, stream, Whh0, Wih0, fcw, w0f);
  hipLaunchKernelGGL(k_build_w1f, dim3(NGATE), dim3(256), 0, stream, Wih1, Whh1, w1f);
  hipLaunchKernelGGL(k_build_bias, dim3(16), dim3(256), 0, stream,
                     bih0, bhh0, bih1, bhh1, Wih0, fcb, bias0b, bias0x, bias1);
  hipLaunchKernelGGL(k_fcwb, dim3(256), dim3(256), 0, stream, fcw, fcwb);
  hipLaunchKernelGGL(k_init, dim3(BATCH), dim3(256), 0, stream, zs, zk, fiw, fib, xa0, xb0);

  Params prm;
  prm.w0f = w0f; prm.w1f = w1f;
  prm.bias0b = bias0b; prm.bias0x = bias0x; prm.bias1 = bias1;
  prm.xa0 = xa0; prm.xa1 = xa1; prm.xb0 = xb0; prm.xb1 = xb1;
  prm.fcwb = fcwb; prm.fcb = fcb; prm.out = out;
  prm.flags = flags;

  hipFuncSetAttribute((const void*)k_lstm, hipFuncAttributeMaxDynamicSharedMemorySize, LDS_BYTES);
  void* args[] = { &prm };
  hipLaunchCooperativeKernel((void*)k_lstm, dim3(NBLK), dim3(NTHR), args, LDS_BYTES, stream);
}